// Round 3
// baseline (145.716 us; speedup 1.0000x reference)
//
#include <hip/hip_runtime.h>

#define T 8
#define C 512
#define HW 196
#define NSEG 16                  // n
#define NT (NSEG * T)            // 128
#define B_TOT (NSEG * HW)        // 3136
#define NH 4
#define KK 5
#define NO 20                    // NH*KK
#define S_SPLIT 8                // c split for k_logits
#define CCH (C / S_SPLIT)        // 64 channels per chunk

typedef const __attribute__((address_space(1))) unsigned int g_u32;
typedef __attribute__((address_space(3))) unsigned int l_u32;

// ---------------------------------------------------------------------------
// Kernel A1: partial logits over a 64-channel chunk, LDS-staged.
// grid (98, 8); 256 threads. Async global->LDS (double-buffered) so the
// compiler CANNOT collapse the prefetch into a dependent load-use chain
// (R1/R2 failure: VGPR=24, VALUBusy 7%).
// ---------------------------------------------------------------------------
__global__ __launch_bounds__(256) void k_logits(const float* __restrict__ x,
                                                const float* __restrict__ W,
                                                float* __restrict__ pl) {
    const int tid = threadIdx.x;
    const int idx = blockIdx.x * 256 + tid;     // position (nt, hw)
    const int nt  = idx / HW;
    const int hw  = idx - nt * HW;
    const int s   = blockIdx.y;
    const int cbase = s * CCH;
    const int wave  = tid >> 6;

    __shared__ float lds[2][8][256];            // [buf][chan-in-chunk][pos]

    const float* xp = x + ((size_t)nt * C + cbase) * HW + hw;

    // issue chunk 0 (8 independent async direct-to-LDS loads)
#pragma unroll
    for (int u = 0; u < 8; ++u)
        __builtin_amdgcn_global_load_lds((g_u32*)(xp + u * HW),
                                         (l_u32*)&lds[0][u][wave * 64], 4, 0, 0);

    float acc[NO];
#pragma unroll
    for (int o = 0; o < NO; ++o) acc[o] = 0.f;

    __syncthreads();

#pragma unroll
    for (int ch = 0; ch < 8; ++ch) {
        const int buf = ch & 1;
        if (ch + 1 < 8) {                        // prefetch next chunk
#pragma unroll
            for (int u = 0; u < 8; ++u)
                __builtin_amdgcn_global_load_lds(
                    (g_u32*)(xp + ((ch + 1) * 8 + u) * HW),
                    (l_u32*)&lds[buf ^ 1][u][wave * 64], 4, 0, 0);
        }
        float xv[8];
#pragma unroll
        for (int u = 0; u < 8; ++u) xv[u] = lds[buf][u][tid];  // conflict-free
        const float* wr = W + cbase + ch * 8;    // wave-uniform -> s_load
#pragma unroll
        for (int o = 0; o < NO; ++o)
#pragma unroll
            for (int u = 0; u < 8; ++u)
                acc[o] = fmaf(xv[u], wr[o * C + u], acc[o]);
        __syncthreads();                         // drains prefetch + buffer reuse
    }

    // pl layout: [s][nt][o][hw]
    float* pp = pl + ((size_t)(s * NT + nt) * NO) * HW + hw;
#pragma unroll
    for (int o = 0; o < NO; ++o) pp[o * HW] = acc[o];
}

// ---------------------------------------------------------------------------
// Kernel A2: reduce 8 partials, softmax over 5 taps, float4 over b.
// 98 blocks x 256 threads; one thread = (t, h, 4 consecutive b).
// ---------------------------------------------------------------------------
__global__ __launch_bounds__(256) void k_softmax(const float* __restrict__ pl,
                                                 float* __restrict__ wgt) {
    const int flat = blockIdx.x * 256 + threadIdx.x;  // < 25088
    const int b4   = flat % (B_TOT / 4);
    const int th   = flat / (B_TOT / 4);
    const int h    = th & 3;
    const int t    = th >> 2;
    const int b    = b4 * 4;
    const int n    = b / HW;                           // 196%4==0: no straddle
    const int hw   = b - n * HW;
    const int nt   = n * T + t;

    float lg[KK][4];
#pragma unroll
    for (int k = 0; k < KK; ++k) {
        float s0 = 0.f, s1 = 0.f, s2 = 0.f, s3 = 0.f;
#pragma unroll
        for (int s = 0; s < S_SPLIT; ++s) {
            const float4 v = *(const float4*)&pl[((size_t)(s * NT + nt) * NO + h * KK + k) * HW + hw];
            s0 += v.x; s1 += v.y; s2 += v.z; s3 += v.w;
        }
        lg[k][0] = s0; lg[k][1] = s1; lg[k][2] = s2; lg[k][3] = s3;
    }

    float wv[KK][4];
#pragma unroll
    for (int j = 0; j < 4; ++j) {
        float m = lg[0][j];
#pragma unroll
        for (int k = 1; k < KK; ++k) m = fmaxf(m, lg[k][j]);
        float e[KK];
        float sum = 0.f;
#pragma unroll
        for (int k = 0; k < KK; ++k) { e[k] = __expf(lg[k][j] - m); sum += e[k]; }
        const float r = 1.f / sum;
#pragma unroll
        for (int k = 0; k < KK; ++k) wv[k][j] = e[k] * r;
    }

#pragma unroll
    for (int k = 0; k < KK; ++k) {
        const float4 o4 = make_float4(wv[k][0], wv[k][1], wv[k][2], wv[k][3]);
        *(float4*)&wgt[((size_t)((t * NH + h) * KK + k)) * B_TOT + b] = o4;
    }
}

// ---------------------------------------------------------------------------
// Kernel B: causal dynamic conv. One thread = (n, channel-pair, 4 hw).
// float4 loads/stores everywhere; weights amortized over 2 channels.
// 784 blocks x 256 threads.
// ---------------------------------------------------------------------------
__global__ __launch_bounds__(256) void k_conv(const float* __restrict__ x,
                                              const float* __restrict__ wgt,
                                              float* __restrict__ out) {
    const int flat = blockIdx.x * 256 + threadIdx.x;  // < 16*256*49
    const int q    = flat % 49;
    const int rest = flat / 49;
    const int cp   = rest & 255;                       // channel pair
    const int n    = rest >> 8;
    const int c    = cp * 2;                           // pair never straddles head
    const int h    = c >> 7;
    const int hw   = q * 4;
    const int b    = n * HW + hw;

    const size_t xbase = ((size_t)(n * T) * C + c) * HW + hw;

    float4 xv[2][T];
#pragma unroll
    for (int t = 0; t < T; ++t) {
        xv[0][t] = *(const float4*)&x[xbase + (size_t)t * C * HW];
        xv[1][t] = *(const float4*)&x[xbase + (size_t)t * C * HW + HW];
    }

#pragma unroll
    for (int t = 0; t < T; ++t) {
        float4 w4[KK];
#pragma unroll
        for (int k = 0; k < KK; ++k)
            w4[k] = *(const float4*)&wgt[((size_t)((t * NH + h) * KK + k)) * B_TOT + b];
#pragma unroll
        for (int ci = 0; ci < 2; ++ci) {
            float4 a = make_float4(0.f, 0.f, 0.f, 0.f);
#pragma unroll
            for (int k = 0; k < KK; ++k) {
                const int j = t + k - 4;               // causal, zero-pad left
                if (j >= 0) {
                    a.x = fmaf(w4[k].x, xv[ci][j].x, a.x);
                    a.y = fmaf(w4[k].y, xv[ci][j].y, a.y);
                    a.z = fmaf(w4[k].z, xv[ci][j].z, a.z);
                    a.w = fmaf(w4[k].w, xv[ci][j].w, a.w);
                }
            }
            *(float4*)&out[xbase + (size_t)t * C * HW + ci * HW] = a;
        }
    }
}

// ---------------------------------------------------------------------------
extern "C" void kernel_launch(void* const* d_in, const int* in_sizes, int n_in,
                              void* d_out, int out_size, void* d_ws, size_t ws_size,
                              hipStream_t stream) {
    const float* x = (const float*)d_in[0];   // (128, 512, 14, 14)
    const float* W = (const float*)d_in[1];   // (20, 512)
    float* out = (float*)d_out;               // (128, 512, 14, 14)

    float* pl  = (float*)d_ws;                             // 16.1 MB
    float* wgt = pl + (size_t)S_SPLIT * NT * NO * HW;      // 2.0 MB

    k_logits<<<dim3(25088 / 256, S_SPLIT), 256, 0, stream>>>(x, W, pl);
    k_softmax<<<dim3(25088 / 256), 256, 0, stream>>>(pl, wgt);
    k_conv<<<dim3((NSEG * 256 * 49) / 256), 256, 0, stream>>>(x, wgt, out);
}

// Round 4
// 144.143 us; speedup vs baseline: 1.0109x; 1.0109x over previous
//
#include <hip/hip_runtime.h>

#define T 8
#define C 512
#define HW 196
#define NSEG 16                  // n
#define NT (NSEG * T)            // 128
#define B_TOT (NSEG * HW)        // 3136
#define NH 4
#define KK 5
#define NO 20                    // NH*KK
#define LDS_STRIDE 21            // 20 + 1 pad -> conflict-free

// ---------------------------------------------------------------------------
// Kernel 1: FUSED logits + chunk-reduction + softmax -> wgt (T*NO, B).
// grid 392, block 512 (8 waves). wave w = channel chunk [w*64, w*64+64);
// lane = position. W address is wave-uniform (readfirstlane) -> s_load path.
// Main loop: 8-deep rotated load batches, pinned with sched_barrier(0) so the
// compiler cannot re-fuse loads into the FMA chain (R1 failure: VGPR=24,
// VALUBusy 7%). Partials reduced through LDS; softmax in-block.
// ---------------------------------------------------------------------------
__global__ __launch_bounds__(512) void k_fused(const float* __restrict__ x,
                                               const float* __restrict__ W,
                                               float* __restrict__ wgt) {
    const int tid = threadIdx.x;
    const int p   = tid & 63;                         // position lane
    const int s   = __builtin_amdgcn_readfirstlane(tid >> 6);  // chunk (SGPR)

    const int idx = blockIdx.x * 64 + p;              // (nt, hw) flat
    const int nt  = idx / HW;
    const int hw  = idx - nt * HW;

    __shared__ float lds[8 * 64 * LDS_STRIDE];        // partials, 43 KB
    __shared__ float lds2[NO * 64];                   // logits/weights, 5 KB

    const float* xp = x + ((size_t)nt * C + s * 64) * HW + hw;
    const float* Wp = W + s * 64;                     // wave-uniform

    float acc[NO];
#pragma unroll
    for (int o = 0; o < NO; ++o) acc[o] = 0.f;

    float xv[2][8];
#pragma unroll
    for (int u = 0; u < 8; ++u) xv[0][u] = xp[u * HW];   // batch 0

#pragma unroll
    for (int cb = 0; cb < 8; ++cb) {
        const int cur = cb & 1;
        if (cb + 1 < 8) {                             // rotated prefetch batch
#pragma unroll
            for (int u = 0; u < 8; ++u)
                xv[cur ^ 1][u] = xp[((cb + 1) * 8 + u) * HW];
        }
        __builtin_amdgcn_sched_barrier(0);            // loads stay above FMAs
        const float* wr = Wp + cb * 8;
#pragma unroll
        for (int o = 0; o < NO; ++o)
#pragma unroll
            for (int u = 0; u < 8; ++u)
                acc[o] = fmaf(xv[cur][u], wr[o * C + u], acc[o]);
    }

    // partials -> LDS (stride 21: odd -> 2-way max, free)
    float* lp = &lds[(s * 64 + p) * LDS_STRIDE];
#pragma unroll
    for (int o = 0; o < NO; ++o) lp[o] = acc[o];
    __syncthreads();

    // stage 1: reduce 8 chunks -> logits in lds2[o][p]
    for (int i = tid; i < NO * 64; i += 512) {
        const int o = i >> 6, pp = i & 63;
        float sm = 0.f;
#pragma unroll
        for (int s2 = 0; s2 < 8; ++s2)
            sm += lds[(s2 * 64 + pp) * LDS_STRIDE + o];
        lds2[o * 64 + pp] = sm;
    }
    __syncthreads();

    // stage 2: softmax over 5 taps per (position, head), in place
    if (tid < 256) {
        const int pp = tid & 63;
        const int h  = tid >> 6;
        float lg[KK];
#pragma unroll
        for (int k = 0; k < KK; ++k) lg[k] = lds2[(h * KK + k) * 64 + pp];
        float m = lg[0];
#pragma unroll
        for (int k = 1; k < KK; ++k) m = fmaxf(m, lg[k]);
        float e[KK], sum = 0.f;
#pragma unroll
        for (int k = 0; k < KK; ++k) { e[k] = __expf(lg[k] - m); sum += e[k]; }
        const float r = 1.f / sum;
#pragma unroll
        for (int k = 0; k < KK; ++k) lds2[(h * KK + k) * 64 + pp] = e[k] * r;
    }
    __syncthreads();

    // stage 3: coalesced store, wgt layout [t][h][k][b]
    for (int i = tid; i < NO * 64; i += 512) {
        const int o  = i >> 6, pp = i & 63;
        const int id = blockIdx.x * 64 + pp;
        const int nt2 = id / HW;
        const int hw2 = id - nt2 * HW;
        const int n2 = nt2 >> 3, t2 = nt2 & 7;
        const int b  = n2 * HW + hw2;
        wgt[(size_t)(t2 * NO + o) * B_TOT + b] = lds2[o * 64 + pp];
    }
}

// ---------------------------------------------------------------------------
// Kernel 2: causal dynamic conv. One thread = (n, c, 4 hw). 1568 blocks
// (~6/CU, ~24 waves/CU -> TLP hides latency). float4 loads/stores; wgt
// re-reads served by L2 (2 MB resident per XCD).
// ---------------------------------------------------------------------------
__global__ __launch_bounds__(256) void k_conv(const float* __restrict__ x,
                                              const float* __restrict__ wgt,
                                              float* __restrict__ out) {
    const int flat = blockIdx.x * 256 + threadIdx.x;   // < 16*512*49
    const int q    = flat % 49;
    const int rest = flat / 49;
    const int c    = rest & 511;
    const int n    = rest >> 9;
    const int h    = c >> 7;                           // head
    const int hw   = q * 4;
    const int b    = n * HW + hw;

    const size_t xbase = ((size_t)(n * T) * C + c) * HW + hw;

    float4 xv[T];
#pragma unroll
    for (int t = 0; t < T; ++t)
        xv[t] = *(const float4*)&x[xbase + (size_t)t * C * HW];

#pragma unroll
    for (int t = 0; t < T; ++t) {
        float4 w4[KK];
#pragma unroll
        for (int k = 0; k < KK; ++k)
            w4[k] = *(const float4*)&wgt[(size_t)((t * NH + h) * KK + k) * B_TOT + b];
        float4 a = make_float4(0.f, 0.f, 0.f, 0.f);
#pragma unroll
        for (int k = 0; k < KK; ++k) {
            const int j = t + k - 4;                   // causal, zero-pad left
            if (j >= 0) {
                a.x = fmaf(w4[k].x, xv[j].x, a.x);
                a.y = fmaf(w4[k].y, xv[j].y, a.y);
                a.z = fmaf(w4[k].z, xv[j].z, a.z);
                a.w = fmaf(w4[k].w, xv[j].w, a.w);
            }
        }
        *(float4*)&out[xbase + (size_t)t * C * HW] = a;
    }
}

// ---------------------------------------------------------------------------
extern "C" void kernel_launch(void* const* d_in, const int* in_sizes, int n_in,
                              void* d_out, int out_size, void* d_ws, size_t ws_size,
                              hipStream_t stream) {
    const float* x = (const float*)d_in[0];   // (128, 512, 14, 14)
    const float* W = (const float*)d_in[1];   // (20, 512)
    float* out = (float*)d_out;               // (128, 512, 14, 14)

    float* wgt = (float*)d_ws;                // 160 * 3136 floats = 2.0 MB

    k_fused<<<dim3(25088 / 64), 512, 0, stream>>>(x, W, wgt);
    k_conv<<<dim3((NSEG * C * 49) / 256), 256, 0, stream>>>(x, wgt, out);
}

// Round 5
// 142.688 us; speedup vs baseline: 1.0212x; 1.0102x over previous
//
#include <hip/hip_runtime.h>

#define T 8
#define C 512
#define HW 196
#define NSEG 16                  // n
#define NT (NSEG * T)            // 128
#define B_TOT (NSEG * HW)        // 3136
#define NPOS (NT * HW)           // 25088 positions
#define NH 4
#define KK 5
#define NO 20                    // NH*KK
#define S_SPLIT 4                // channel split across blocks in k_logits
#define LDS_STRIDE 21            // 20 + 1 pad

// ---------------------------------------------------------------------------
// Kernel 1: partial logits. grid (392, 4), block 256 (4 waves).
// Block (g, s): 64 positions [g*64, g*64+64), channels [s*128, s*128+128).
// Wave w covers 32 channels; lane = position (coalesced x reads).
// 1568 blocks -> ~6 blocks/CU, ~24 waves/CU: TLP covers load latency that
// the depth-1 rotated prefetch cannot (R4 failure: 392 blocks, 2 waves/SIMD).
// W addresses wave-uniform -> s_load_dwordx8 path.
// ---------------------------------------------------------------------------
__global__ __launch_bounds__(256) void k_logits(const float* __restrict__ x,
                                                const float* __restrict__ W,
                                                float* __restrict__ pl) {
    const int tid = threadIdx.x;
    const int p   = tid & 63;                                   // position lane
    const int wv  = __builtin_amdgcn_readfirstlane(tid >> 6);   // wave 0..3
    const int s   = blockIdx.y;

    const int idx = blockIdx.x * 64 + p;          // flat (nt, hw)
    const int nt  = idx / HW;
    const int hw  = idx - nt * HW;
    const int cb  = s * 128 + wv * 32;            // this wave's channel base

    __shared__ float lds[4 * 64 * LDS_STRIDE];    // per-wave partials, 21.5 KB

    const float* xp = x + ((size_t)nt * C + cb) * HW + hw;
    const float* Wp = W + cb;                     // wave-uniform

    float acc[NO];
#pragma unroll
    for (int o = 0; o < NO; ++o) acc[o] = 0.f;

    float xv[2][8];
#pragma unroll
    for (int u = 0; u < 8; ++u) xv[0][u] = xp[u * HW];     // batch 0

#pragma unroll
    for (int bt = 0; bt < 4; ++bt) {              // 4 batches of 8 channels
        const int cur = bt & 1;
        if (bt + 1 < 4) {                         // rotated prefetch
#pragma unroll
            for (int u = 0; u < 8; ++u)
                xv[cur ^ 1][u] = xp[((bt + 1) * 8 + u) * HW];
        }
        __builtin_amdgcn_sched_barrier(0);        // keep loads above the FMAs
        const float* wr = Wp + bt * 8;
#pragma unroll
        for (int o = 0; o < NO; ++o)
#pragma unroll
            for (int u = 0; u < 8; ++u)
                acc[o] = fmaf(xv[cur][u], wr[o * C + u], acc[o]);
    }

    // reduce the 4 waves through LDS (stride 21: gcd(21,32)=1, conflict-free)
    float* lp = &lds[(wv * 64 + p) * LDS_STRIDE];
#pragma unroll
    for (int o = 0; o < NO; ++o) lp[o] = acc[o];
    __syncthreads();

    // pl layout: [s][o][idx] -- coalesced over idx
    for (int i = tid; i < NO * 64; i += 256) {
        const int o = i >> 6, pp = i & 63;
        float sm = 0.f;
#pragma unroll
        for (int w2 = 0; w2 < 4; ++w2)
            sm += lds[(w2 * 64 + pp) * LDS_STRIDE + o];
        pl[((size_t)(s * NO + o)) * NPOS + blockIdx.x * 64 + pp] = sm;
    }
}

// ---------------------------------------------------------------------------
// Kernel 2: reduce 4 chunk-partials + softmax. grid 392, block 256.
// One thread = (head, position). Reads coalesced over idx.
// ---------------------------------------------------------------------------
__global__ __launch_bounds__(256) void k_softmax(const float* __restrict__ pl,
                                                 float* __restrict__ wgt) {
    const int f   = blockIdx.x * 256 + threadIdx.x;   // < 4 * 25088
    const int h   = f / NPOS;
    const int idx = f - h * NPOS;

    float lg[KK];
#pragma unroll
    for (int k = 0; k < KK; ++k) {
        float sm = 0.f;
#pragma unroll
        for (int s = 0; s < S_SPLIT; ++s)
            sm += pl[((size_t)(s * NO + h * KK + k)) * NPOS + idx];
        lg[k] = sm;
    }

    float m = lg[0];
#pragma unroll
    for (int k = 1; k < KK; ++k) m = fmaxf(m, lg[k]);
    float e[KK], sum = 0.f;
#pragma unroll
    for (int k = 0; k < KK; ++k) { e[k] = __expf(lg[k] - m); sum += e[k]; }
    const float r = 1.f / sum;

    const int nt = idx / HW;
    const int hw = idx - nt * HW;
    const int n  = nt >> 3, t = nt & 7;
    const int b  = n * HW + hw;
#pragma unroll
    for (int k = 0; k < KK; ++k)
        wgt[((size_t)((t * NH + h) * KK + k)) * B_TOT + b] = e[k] * r;
}

// ---------------------------------------------------------------------------
// Kernel 3: causal dynamic conv. One thread = (n, 4-channel group, hw),
// scalar loads/stores (R2 evidence: TLP > vectorization here). Weights
// loaded once per thread, reused across 4 channels: wgt traffic 257->64 MB.
// 1568 blocks -> deep TLP; ci-iterations independent (no barriers) -> ILP.
// ---------------------------------------------------------------------------
__global__ __launch_bounds__(256) void k_conv(const float* __restrict__ x,
                                              const float* __restrict__ wgt,
                                              float* __restrict__ out) {
    const int f  = blockIdx.x * 256 + threadIdx.x;  // < 16*128*196
    const int hw = f % HW;
    const int r  = f / HW;
    const int cg = r & 127;                          // 4-channel group
    const int n  = r >> 7;
    const int c0 = cg * 4;
    const int h  = cg >> 5;                          // head (128 ch/head)
    const int b  = n * HW + hw;

    float w[T][KK];
#pragma unroll
    for (int t = 0; t < T; ++t)
#pragma unroll
        for (int k = 0; k < KK; ++k)
            w[t][k] = wgt[((size_t)((t * NH + h) * KK + k)) * B_TOT + b];

#pragma unroll
    for (int ci = 0; ci < 4; ++ci) {
        const size_t base = ((size_t)(n * T) * C + (c0 + ci)) * HW + hw;
        float xv[T];
#pragma unroll
        for (int t = 0; t < T; ++t) xv[t] = x[base + (size_t)t * C * HW];
#pragma unroll
        for (int t = 0; t < T; ++t) {
            float a = 0.f;
#pragma unroll
            for (int k = 0; k < KK; ++k) {
                const int j = t + k - 4;             // causal, zero-pad left
                if (j >= 0) a = fmaf(w[t][k], xv[j], a);
            }
            out[base + (size_t)t * C * HW] = a;
        }
    }
}

// ---------------------------------------------------------------------------
extern "C" void kernel_launch(void* const* d_in, const int* in_sizes, int n_in,
                              void* d_out, int out_size, void* d_ws, size_t ws_size,
                              hipStream_t stream) {
    const float* x = (const float*)d_in[0];   // (128, 512, 14, 14)
    const float* W = (const float*)d_in[1];   // (20, 512)
    float* out = (float*)d_out;               // (128, 512, 14, 14)

    float* pl  = (float*)d_ws;                        // 4*20*25088 fl = 8.0 MB
    float* wgt = pl + (size_t)S_SPLIT * NO * NPOS;    // 160*3136 fl = 2.0 MB

    k_logits<<<dim3(NPOS / 64, S_SPLIT), 256, 0, stream>>>(x, W, pl);
    k_softmax<<<dim3(NH * NPOS / 256), 256, 0, stream>>>(pl, wgt);
    k_conv<<<dim3(NSEG * 128 * HW / 256), 256, 0, stream>>>(x, wgt, out);
}

// Round 6
// 139.190 us; speedup vs baseline: 1.0469x; 1.0251x over previous
//
#include <hip/hip_runtime.h>

#define T 8
#define C 512
#define HW 196
#define NSEG 16                  // n
#define NT (NSEG * T)            // 128
#define B_TOT (NSEG * HW)        // 3136
#define NPOS (NT * HW)           // 25088 positions
#define NH 4
#define KK 5
#define NO 20                    // NH*KK
#define S_SPLIT 16               // channel split across blocks in k_logits
#define CCH (C / S_SPLIT)        // 32 channels per block

// ---------------------------------------------------------------------------
// Kernel 1: partial logits. grid (98, 16), block 256. One thread = one
// (nt,hw) position x 32 channels. Deliberately the SIMPLE compiler-fused
// loop (R1/R2 structure, VGPR~24): every ILP trick (LDS async R3, rotated
// prefetch R4/R5) lost to plain TLP. 1568 blocks -> ~24 waves/CU; 24 waves
// x 2-4 naturally-in-flight loads covers the ~900cyc HBM latency.
// W is block-uniform -> scalar loads.
// ---------------------------------------------------------------------------
__global__ __launch_bounds__(256) void k_logits(const float* __restrict__ x,
                                                const float* __restrict__ W,
                                                float* __restrict__ pl) {
    const int idx = blockIdx.x * 256 + threadIdx.x;   // 0..25087
    const int nt  = idx / HW;
    const int hw  = idx - nt * HW;
    const int s   = blockIdx.y;                       // 0..15
    const int cb  = s * CCH;

    const float* xp = x + ((size_t)nt * C + cb) * HW + hw;

    float acc[NO];
#pragma unroll
    for (int o = 0; o < NO; ++o) acc[o] = 0.f;

#pragma unroll
    for (int c0 = 0; c0 < CCH; c0 += 4) {
        // 4 independent loads per chain step (halves effective latency/load)
        const float x0 = xp[(c0 + 0) * HW];
        const float x1 = xp[(c0 + 1) * HW];
        const float x2 = xp[(c0 + 2) * HW];
        const float x3 = xp[(c0 + 3) * HW];
        const float* wr = W + cb + c0;                // block-uniform
#pragma unroll
        for (int o = 0; o < NO; ++o) {
            float a = acc[o];
            a = fmaf(x0, wr[o * C + 0], a);
            a = fmaf(x1, wr[o * C + 1], a);
            a = fmaf(x2, wr[o * C + 2], a);
            a = fmaf(x3, wr[o * C + 3], a);
            acc[o] = a;
        }
    }

    // pl layout: [s][o][idx] -- coalesced over idx
    float* pp = pl + (size_t)(s * NO) * NPOS + idx;
#pragma unroll
    for (int o = 0; o < NO; ++o) pp[(size_t)o * NPOS] = acc[o];
}

// ---------------------------------------------------------------------------
// Kernel 2: reduce 16 chunk-partials + softmax. 784 blocks x 128 threads
// (R2's version had only 98 blocks -- starved). One thread = (head, pos).
// 5 independent 16-deep sum chains per thread; all reads coalesced over idx.
// ---------------------------------------------------------------------------
__global__ __launch_bounds__(128) void k_softmax(const float* __restrict__ pl,
                                                 float* __restrict__ wgt) {
    const int f   = blockIdx.x * 128 + threadIdx.x;   // < 4 * 25088
    const int h   = f / NPOS;
    const int idx = f - h * NPOS;

    float lg[KK];
#pragma unroll
    for (int k = 0; k < KK; ++k) lg[k] = 0.f;
#pragma unroll
    for (int s = 0; s < S_SPLIT; ++s)
#pragma unroll
        for (int k = 0; k < KK; ++k)
            lg[k] += pl[(size_t)(s * NO + h * KK + k) * NPOS + idx];

    float m = lg[0];
#pragma unroll
    for (int k = 1; k < KK; ++k) m = fmaxf(m, lg[k]);
    float e[KK], sum = 0.f;
#pragma unroll
    for (int k = 0; k < KK; ++k) { e[k] = __expf(lg[k] - m); sum += e[k]; }
    const float r = 1.f / sum;

    const int nt = idx / HW;
    const int hw = idx - nt * HW;
    const int n  = nt >> 3, t = nt & 7;
    const int b  = n * HW + hw;
#pragma unroll
    for (int k = 0; k < KK; ++k)
        wgt[((size_t)((t * NH + h) * KK + k)) * B_TOT + b] = e[k] * r;
}

// ---------------------------------------------------------------------------
// Kernel 3: causal dynamic conv -- EXACT R2 winner. One thread = (n, c, hw)
// scalar; 6272 blocks (8 resident/CU -> ~32 waves/CU, pure TLP). wgt (2 MB)
// is L2-resident; x re-read served by L3.
// ---------------------------------------------------------------------------
__global__ __launch_bounds__(256) void k_conv(const float* __restrict__ x,
                                              const float* __restrict__ wgt,
                                              float* __restrict__ out) {
    const int idx = blockIdx.x * 256 + threadIdx.x;  // < 16*512*196
    const int hw  = idx % HW;
    const int t1  = idx / HW;          // n*C + c
    const int c   = t1 % C;
    const int n   = t1 / C;
    const int h   = c >> 7;            // head
    const int b   = n * HW + hw;

    float w[T][KK];
#pragma unroll
    for (int t = 0; t < T; ++t)
#pragma unroll
        for (int k = 0; k < KK; ++k)
            w[t][k] = wgt[((size_t)((t * NH + h) * KK + k)) * B_TOT + b];

    const size_t base = ((size_t)(n * T) * C + c) * HW + hw;
    float xv[T];
#pragma unroll
    for (int t = 0; t < T; ++t) xv[t] = x[base + (size_t)t * C * HW];

#pragma unroll
    for (int t = 0; t < T; ++t) {
        float acc = 0.f;
#pragma unroll
        for (int k = 0; k < KK; ++k) {
            const int j = t + k - 4;   // causal, zero-padded left
            if (j >= 0) acc = fmaf(w[t][k], xv[j], acc);
        }
        out[base + (size_t)t * C * HW] = acc;
    }
}

// ---------------------------------------------------------------------------
extern "C" void kernel_launch(void* const* d_in, const int* in_sizes, int n_in,
                              void* d_out, int out_size, void* d_ws, size_t ws_size,
                              hipStream_t stream) {
    const float* x = (const float*)d_in[0];   // (128, 512, 14, 14)
    const float* W = (const float*)d_in[1];   // (20, 512)
    float* out = (float*)d_out;               // (128, 512, 14, 14)

    float* pl  = (float*)d_ws;                        // 16*20*25088 fl = 32 MB
    float* wgt = pl + (size_t)S_SPLIT * NO * NPOS;    // 160*3136 fl = 2 MB

    k_logits<<<dim3(NPOS / 256, S_SPLIT), 256, 0, stream>>>(x, W, pl);
    k_softmax<<<dim3(NH * NPOS / 128), 128, 0, stream>>>(pl, wgt);
    k_conv<<<dim3(NSEG * C * HW / 256), 256, 0, stream>>>(x, wgt, out);
}

// Round 7
// 126.550 us; speedup vs baseline: 1.1514x; 1.0999x over previous
//
#include <hip/hip_runtime.h>
#include <hip/hip_bf16.h>

#define T 8
#define C 512
#define HW 196
#define NSEG 16                  // n
#define NT (NSEG * T)            // 128
#define B_TOT (NSEG * HW)        // 3136
#define NPOS (NT * HW)           // 25088 positions
#define NH 4
#define KK 5
#define NO 20                    // NH*KK
#define S_SPLIT 16               // channel split across blocks in k_logits
#define CCH (C / S_SPLIT)        // 32 channels per block

// ---------------------------------------------------------------------------
// Kernel 1: partial logits -> bf16. grid (196, 16), block 128 -> 3136 blocks
// (fine dispatch granularity, ~24 waves/CU sustained). Per thread: 2 batches
// of 16 independent staged loads (xv[16] array, FMAs strictly after) ->
// 16-deep MLP per wave. #pragma unroll 1 on the batch loop caps VGPR <= 64
// so 8 waves/SIMD remain eligible. W is block-uniform -> scalar loads.
// R5 failure mode (4-deep window, 12 waves/CU -> 1.15 TB/s) addressed by
// BOTH deeper per-wave window and more waves.
// ---------------------------------------------------------------------------
__global__ __launch_bounds__(128) void k_logits(const float* __restrict__ x,
                                                const float* __restrict__ W,
                                                __hip_bfloat16* __restrict__ pl) {
    const int idx = blockIdx.x * 128 + threadIdx.x;   // 0..25087
    const int nt  = idx / HW;
    const int hw  = idx - nt * HW;
    const int s   = blockIdx.y;                       // 0..15
    const int cb  = s * CCH;

    const float* xp = x + ((size_t)nt * C + cb) * HW + hw;

    float acc[NO];
#pragma unroll
    for (int o = 0; o < NO; ++o) acc[o] = 0.f;

#pragma unroll 1
    for (int half = 0; half < 2; ++half) {
        float xv[16];                                  // 16 independent loads
#pragma unroll
        for (int u = 0; u < 16; ++u)
            xv[u] = xp[(half * 16 + u) * HW];
        const float* wr = W + cb + half * 16;          // block-uniform
#pragma unroll
        for (int o = 0; o < NO; ++o) {
            float a = acc[o];
#pragma unroll
            for (int u = 0; u < 16; ++u)
                a = fmaf(xv[u], wr[o * C + u], a);
            acc[o] = a;
        }
    }

    // pl layout: [s][o][idx] bf16 -- coalesced over idx
    __hip_bfloat16* pp = pl + (size_t)(s * NO) * NPOS + idx;
#pragma unroll
    for (int o = 0; o < NO; ++o)
        pp[(size_t)o * NPOS] = __float2bfloat16(acc[o]);
}

// ---------------------------------------------------------------------------
// Kernel 2: reduce 16 bf16 partials + softmax. 784 blocks x 128 threads.
// One thread = (head, position); 80 independent coalesced loads -> deep MLP
// even at modest occupancy.
// ---------------------------------------------------------------------------
__global__ __launch_bounds__(128) void k_softmax(const __hip_bfloat16* __restrict__ pl,
                                                 __hip_bfloat16* __restrict__ wgt) {
    const int f   = blockIdx.x * 128 + threadIdx.x;   // < 4 * 25088
    const int h   = f / NPOS;
    const int idx = f - h * NPOS;

    float lg[KK];
#pragma unroll
    for (int k = 0; k < KK; ++k) lg[k] = 0.f;
#pragma unroll
    for (int s = 0; s < S_SPLIT; ++s)
#pragma unroll
        for (int k = 0; k < KK; ++k)
            lg[k] += __bfloat162float(pl[(size_t)(s * NO + h * KK + k) * NPOS + idx]);

    float m = lg[0];
#pragma unroll
    for (int k = 1; k < KK; ++k) m = fmaxf(m, lg[k]);
    float e[KK], sum = 0.f;
#pragma unroll
    for (int k = 0; k < KK; ++k) { e[k] = __expf(lg[k] - m); sum += e[k]; }
    const float r = 1.f / sum;

    const int nt = idx / HW;
    const int hw = idx - nt * HW;
    const int n  = nt >> 3, t = nt & 7;
    const int b  = n * HW + hw;
#pragma unroll
    for (int k = 0; k < KK; ++k)
        wgt[((size_t)((t * NH + h) * KK + k)) * B_TOT + b] = __float2bfloat16(e[k] * r);
}

// ---------------------------------------------------------------------------
// Kernel 3: causal dynamic conv -- R2 winner shape. One thread = (n, c, hw)
// scalar; 6272 blocks (pure TLP). wgt now bf16 (1 MB -> fully L2-resident);
// x re-read served by L3; out stores fire-and-forget.
// ---------------------------------------------------------------------------
__global__ __launch_bounds__(256) void k_conv(const float* __restrict__ x,
                                              const __hip_bfloat16* __restrict__ wgt,
                                              float* __restrict__ out) {
    const int idx = blockIdx.x * 256 + threadIdx.x;  // < 16*512*196
    const int hw  = idx % HW;
    const int t1  = idx / HW;          // n*C + c
    const int c   = t1 % C;
    const int n   = t1 / C;
    const int h   = c >> 7;            // head
    const int b   = n * HW + hw;

    float w[T][KK];
#pragma unroll
    for (int t = 0; t < T; ++t)
#pragma unroll
        for (int k = 0; k < KK; ++k)
            w[t][k] = __bfloat162float(
                wgt[((size_t)((t * NH + h) * KK + k)) * B_TOT + b]);

    const size_t base = ((size_t)(n * T) * C + c) * HW + hw;
    float xv[T];
#pragma unroll
    for (int t = 0; t < T; ++t) xv[t] = x[base + (size_t)t * C * HW];

#pragma unroll
    for (int t = 0; t < T; ++t) {
        float acc = 0.f;
#pragma unroll
        for (int k = 0; k < KK; ++k) {
            const int j = t + k - 4;   // causal, zero-padded left
            if (j >= 0) acc = fmaf(w[t][k], xv[j], acc);
        }
        out[base + (size_t)t * C * HW] = acc;
    }
}

// ---------------------------------------------------------------------------
extern "C" void kernel_launch(void* const* d_in, const int* in_sizes, int n_in,
                              void* d_out, int out_size, void* d_ws, size_t ws_size,
                              hipStream_t stream) {
    const float* x = (const float*)d_in[0];   // (128, 512, 14, 14)
    const float* W = (const float*)d_in[1];   // (20, 512)
    float* out = (float*)d_out;               // (128, 512, 14, 14)

    __hip_bfloat16* pl  = (__hip_bfloat16*)d_ws;            // 16*20*25088*2B = 16 MB
    __hip_bfloat16* wgt = pl + (size_t)S_SPLIT * NO * NPOS; // 160*3136*2B = 1 MB

    k_logits<<<dim3(NPOS / 128, S_SPLIT), 128, 0, stream>>>(x, W, pl);
    k_softmax<<<dim3(NH * NPOS / 128), 128, 0, stream>>>(pl, wgt);
    k_conv<<<dim3(NSEG * C * HW / 256), 256, 0, stream>>>(x, wgt, out);
}